// Round 3
// baseline (269.635 us; speedup 1.0000x reference)
//
#include <hip/hip_runtime.h>
#include <hip/hip_bf16.h>
#include <math.h>

// Problem constants: B=4, T=4096, C=1024, H=64
#define Bn 4
#define Tn 4096
#define Cn 1024
#define Hn 64

typedef __bf16 bf16_t;
typedef __bf16 bf16x8 __attribute__((ext_vector_type(8)));
typedef float f32x4 __attribute__((ext_vector_type(4)));

// bf16 workspace layout (elements)
#define WT_OFF 0
#define Q_OFF  196608
#define K_OFF  (Q_OFF + 1048576)
#define VT_OFF (K_OFF + 1048576)
#define BF16_WS_ELEMS (VT_OFF + 1048576)   // 3,342,336 el -> 6,684,672 bytes

// ---------------------------------------------------------------------------
// Kernel 0: WT[n][k] = W_sel[k][n&63] bf16, with softmax scale*log2(e) folded
// into the Wq rows (n<64). n in [0,192), k in [0,1024)
// ---------------------------------------------------------------------------
__global__ void wt_kernel(const float* __restrict__ Wq, const float* __restrict__ Wk,
                          const float* __restrict__ Wv, bf16_t* __restrict__ WT) {
    int idx = blockIdx.x * 256 + threadIdx.x;   // idx = k*192 + n (coalesced reads)
    int k = idx / 192;
    int n = idx - k * 192;
    const float* W = (n < 64) ? Wq : (n < 128) ? Wk : Wv;
    float s = (n < 64) ? 0.1803368801111204f : 1.0f;   // H^-0.5 * log2(e)
    WT[(size_t)n * 1024 + k] = (bf16_t)(W[(size_t)k * 64 + (n & 63)] * s);
}

// ---------------------------------------------------------------------------
// Kernel 1: QKV projection, barrier-free, no LDS. 256 blocks x 256 thr.
// Wave owns 16 M-rows x all 192 N (12 n-subtiles). A-frags straight from
// global fp32 x (no redundancy); B-frags straight from global WT (L1-shared
// across waves). 1-deep manual prefetch.
// ---------------------------------------------------------------------------
__launch_bounds__(256)
__global__ void proj_kernel(const float* __restrict__ x, const bf16_t* __restrict__ WT,
                            bf16_t* __restrict__ q, bf16_t* __restrict__ kmat,
                            bf16_t* __restrict__ vt) {
    const int tid  = threadIdx.x;
    const int wave = tid >> 6;
    const int lane = tid & 63;
    const int l15  = lane & 15;
    const int quad = lane >> 4;
    const int m0   = blockIdx.x * 64 + wave * 16;

    const float*  xp = x  + (size_t)(m0 + l15) * Cn + quad * 8;
    const bf16_t* wp = WT + (size_t)l15 * Cn + quad * 8;

    f32x4 acc[12];
#pragma unroll
    for (int n = 0; n < 12; ++n) acc[n] = (f32x4){0.f, 0.f, 0.f, 0.f};

    bf16x8 af, bfr[12];
    {
        float4 v0 = *(const float4*)(xp);
        float4 v1 = *(const float4*)(xp + 4);
        af[0] = (bf16_t)v0.x; af[1] = (bf16_t)v0.y; af[2] = (bf16_t)v0.z; af[3] = (bf16_t)v0.w;
        af[4] = (bf16_t)v1.x; af[5] = (bf16_t)v1.y; af[6] = (bf16_t)v1.z; af[7] = (bf16_t)v1.w;
#pragma unroll
        for (int n = 0; n < 12; ++n)
            bfr[n] = *(const bf16x8*)(wp + (size_t)n * 16 * Cn);
    }

    for (int kc = 0; kc < 32; ++kc) {
        bf16x8 af2, bfr2[12];
        if (kc < 31) {
            const float* xn = xp + (kc + 1) * 32;
            float4 v0 = *(const float4*)(xn);
            float4 v1 = *(const float4*)(xn + 4);
            af2[0] = (bf16_t)v0.x; af2[1] = (bf16_t)v0.y; af2[2] = (bf16_t)v0.z; af2[3] = (bf16_t)v0.w;
            af2[4] = (bf16_t)v1.x; af2[5] = (bf16_t)v1.y; af2[6] = (bf16_t)v1.z; af2[7] = (bf16_t)v1.w;
            const bf16_t* wn = wp + (kc + 1) * 32;
#pragma unroll
            for (int n = 0; n < 12; ++n)
                bfr2[n] = *(const bf16x8*)(wn + (size_t)n * 16 * Cn);
        }
#pragma unroll
        for (int n = 0; n < 12; ++n)
            acc[n] = __builtin_amdgcn_mfma_f32_16x16x32_bf16(af, bfr[n], acc[n], 0, 0, 0);
        af = af2;
#pragma unroll
        for (int n = 0; n < 12; ++n) bfr[n] = bfr2[n];
    }

    // epilogue: C/D layout col=lane&15, row=quad*4+reg
    const int rbase = m0 + quad * 4;
#pragma unroll
    for (int ns = 0; ns < 12; ++ns) {
        int n = ns * 16 + l15;
#pragma unroll
        for (int r = 0; r < 4; ++r) {
            int row = rbase + r;
            float v = acc[ns][r];
            if (ns < 4) {
                q[(size_t)row * Hn + n] = (bf16_t)v;
            } else if (ns < 8) {
                kmat[(size_t)row * Hn + (n - 64)] = (bf16_t)v;
            } else {
                int b  = row >> 12;
                int tr = row & (Tn - 1);
                vt[((size_t)b * Hn + (n - 128)) * Tn + tr] = (bf16_t)v;
            }
        }
    }
}

// ---------------------------------------------------------------------------
// Kernel 2: split-KV causal flash attention, barrier-free, no running max
// (scores bounded; exp2 in fp32 cannot overflow; scale cancels in combine).
// Grid (NSMAX, 64, B). K/V frags straight from global (L1-shared across the
// 4 waves); p_lds is wave-private (same-wave lgkm ordering suffices).
// ---------------------------------------------------------------------------
__launch_bounds__(256)
__global__ void attn_part(const bf16_t* __restrict__ q, const bf16_t* __restrict__ kmat,
                          const bf16_t* __restrict__ vt, float* __restrict__ Opart,
                          float* __restrict__ lpart, int UPS, int NSMAX) {
    __shared__ bf16_t p_lds[4][16][72];

    const int tid  = threadIdx.x;
    const int wave = tid >> 6;
    const int lane = tid & 63;
    const int l15  = lane & 15;
    const int quad = lane >> 4;
    const int split = blockIdx.x;
    const int t     = blockIdx.y;   // q-tile 0..63
    const int b     = blockIdx.z;

    const int nsplit = t / UPS + 1;
    if (split >= nsplit) return;
    const int u0 = split * UPS;
    const int u1 = min(u0 + UPS, t + 1);
    const int q0 = t * 64;

    size_t qbase = ((size_t)b * Tn + q0 + wave * 16 + l15) * Hn;
    bf16x8 qf0 = *(const bf16x8*)(q + qbase + quad * 8);
    bf16x8 qf1 = *(const bf16x8*)(q + qbase + 32 + quad * 8);

    const bf16_t* kb = kmat + (size_t)b * Tn * Hn;
    const bf16_t* vb = vt + (size_t)b * Hn * Tn;

    f32x4 acc_o[4];
#pragma unroll
    for (int i = 0; i < 4; ++i) acc_o[i] = (f32x4){0.f, 0.f, 0.f, 0.f};
    float lsum[4] = {0.f, 0.f, 0.f, 0.f};

    for (int u = u0; u < u1; ++u) {
        const int s0 = u * 64;
        // ---- S = Q K^T (scale pre-folded into q) ----
        f32x4 accs[4];
#pragma unroll
        for (int ts = 0; ts < 4; ++ts) accs[ts] = (f32x4){0.f, 0.f, 0.f, 0.f};
#pragma unroll
        for (int ts = 0; ts < 4; ++ts) {
            const bf16_t* kp = kb + (size_t)(s0 + ts * 16 + l15) * Hn + quad * 8;
            bf16x8 kf0 = *(const bf16x8*)(kp);
            bf16x8 kf1 = *(const bf16x8*)(kp + 32);
            accs[ts] = __builtin_amdgcn_mfma_f32_16x16x32_bf16(qf0, kf0, accs[ts], 0, 0, 0);
            accs[ts] = __builtin_amdgcn_mfma_f32_16x16x32_bf16(qf1, kf1, accs[ts], 0, 0, 0);
        }
        // ---- causal mask (diag unit only; wave-uniform branch) ----
        if (u == t) {
            const int rowb = q0 + wave * 16 + quad * 4;
#pragma unroll
            for (int ts = 0; ts < 4; ++ts) {
                int col = s0 + ts * 16 + l15;
#pragma unroll
                for (int r = 0; r < 4; ++r)
                    if (col > rowb + r) accs[ts][r] = -INFINITY;
            }
        }
        // ---- P = exp2(S), accumulate per-lane l, write P to wave-private LDS ----
#pragma unroll
        for (int ts = 0; ts < 4; ++ts) {
#pragma unroll
            for (int r = 0; r < 4; ++r) {
                float p = exp2f(accs[ts][r]);
                lsum[r] += p;
                p_lds[wave][quad * 4 + r][ts * 16 + l15] = (bf16_t)p;
            }
        }
        // ---- O += P V ----
#pragma unroll
        for (int kk = 0; kk < 64; kk += 32) {
            bf16x8 pf = *(const bf16x8*)&p_lds[wave][l15][kk + quad * 8];
#pragma unroll
            for (int t2 = 0; t2 < 4; ++t2) {
                bf16x8 vf = *(const bf16x8*)(vb + (size_t)(t2 * 16 + l15) * Tn + s0 + kk + quad * 8);
                acc_o[t2] = __builtin_amdgcn_mfma_f32_16x16x32_bf16(pf, vf, acc_o[t2], 0, 0, 0);
            }
        }
    }
    // ---- one deferred cross-lane l reduction ----
#pragma unroll
    for (int r = 0; r < 4; ++r) {
        float v = lsum[r];
        v += __shfl_xor(v, 1);
        v += __shfl_xor(v, 2);
        v += __shfl_xor(v, 4);
        v += __shfl_xor(v, 8);
        lsum[r] = v;
    }
    // ---- write partials (unnormalized O, l) ----
    size_t pbase = ((size_t)(b * 64 + t) * NSMAX + split) * 4096;
#pragma unroll
    for (int t2 = 0; t2 < 4; ++t2)
#pragma unroll
        for (int r = 0; r < 4; ++r)
            Opart[pbase + (size_t)(wave * 16 + quad * 4 + r) * 64 + t2 * 16 + l15] = acc_o[t2][r];
    if (l15 == 0) {
        size_t lb = ((size_t)(b * 64 + t) * NSMAX + split) * 64;
#pragma unroll
        for (int r = 0; r < 4; ++r)
            lpart[lb + wave * 16 + quad * 4 + r] = lsum[r];
    }
}

// ---------------------------------------------------------------------------
// Kernel 3: combine partials (plain sums; no max bookkeeping). Grid (64, B).
// ---------------------------------------------------------------------------
__launch_bounds__(256)
__global__ void combine_kernel(const float* __restrict__ Opart, const float* __restrict__ lpart,
                               float* __restrict__ out, int UPS, int NSMAX) {
    const int t = blockIdx.x;
    const int b = blockIdx.y;
    const int ns = t / UPS + 1;
    const int tid = threadIdx.x;
    const int row = tid >> 2;
    const int cg  = tid & 3;

    size_t pbase = (size_t)(b * 64 + t) * NSMAX * 4096;
    size_t lbase = (size_t)(b * 64 + t) * NSMAX * 64;

    float L = 0.f;
    float4 o[4];
#pragma unroll
    for (int i = 0; i < 4; ++i) o[i] = (float4){0.f, 0.f, 0.f, 0.f};
    for (int s = 0; s < ns; ++s) {
        L += lpart[lbase + s * 64 + row];
        const float4* src = (const float4*)(Opart + pbase + (size_t)s * 4096 + (size_t)row * 64 + cg * 16);
#pragma unroll
        for (int i = 0; i < 4; ++i) {
            float4 v = src[i];
            o[i].x += v.x; o[i].y += v.y; o[i].z += v.z; o[i].w += v.w;
        }
    }
    float inv = 1.f / L;
    float* dst = out + ((size_t)b * Tn + t * 64 + row) * Hn + cg * 16;
#pragma unroll
    for (int i = 0; i < 4; ++i) {
        float4 v = o[i];
        v.x *= inv; v.y *= inv; v.z *= inv; v.w *= inv;
        ((float4*)dst)[i] = v;
    }
}

// ---------------------------------------------------------------------------
extern "C" void kernel_launch(void* const* d_in, const int* in_sizes, int n_in,
                              void* d_out, int out_size, void* d_ws, size_t ws_size,
                              hipStream_t stream) {
    const float* x  = (const float*)d_in[0];
    const float* Wq = (const float*)d_in[1];
    const float* Wk = (const float*)d_in[2];
    const float* Wv = (const float*)d_in[3];
    float* out = (float*)d_out;

    bf16_t* wsb = (bf16_t*)d_ws;
    bf16_t* WT = wsb + WT_OFF;
    bf16_t* qb = wsb + Q_OFF;
    bf16_t* kb = wsb + K_OFF;
    bf16_t* vt = wsb + VT_OFF;

    const size_t base = (size_t)BF16_WS_ELEMS * 2;   // bytes used by bf16 region
    int NSMAX = 8;
    while (NSMAX > 1) {
        size_t need = base + (size_t)NSMAX * Bn * 64 * 4096 * 4      // Opart
                           + (size_t)NSMAX * Bn * 64 * 64 * 4;       // lpart
        if (need <= ws_size) break;
        NSMAX >>= 1;
    }
    const int UPS = 64 / NSMAX;

    float* Opart = (float*)((char*)d_ws + base);
    float* lpart = Opart + (size_t)NSMAX * Bn * 64 * 4096;

    wt_kernel<<<dim3(192 * 1024 / 256), dim3(256), 0, stream>>>(Wq, Wk, Wv, WT);
    proj_kernel<<<dim3((Bn * Tn) / 64), dim3(256), 0, stream>>>(x, WT, qb, kb, vt);
    attn_part<<<dim3(NSMAX, Tn / 64, Bn), dim3(256), 0, stream>>>(qb, kb, vt, Opart, lpart, UPS, NSMAX);
    combine_kernel<<<dim3(Tn / 64, Bn), dim3(256), 0, stream>>>(Opart, lpart, out, UPS, NSMAX);
}

// Round 4
// 196.364 us; speedup vs baseline: 1.3731x; 1.3731x over previous
//
#include <hip/hip_runtime.h>
#include <hip/hip_bf16.h>
#include <math.h>

// Problem constants: B=4, T=4096, C=1024, H=64
#define Bn 4
#define Tn 4096
#define Cn 1024
#define Hn 64

typedef __bf16 bf16_t;
typedef __bf16 bf16x8 __attribute__((ext_vector_type(8)));
typedef float f32x4 __attribute__((ext_vector_type(4)));

// bf16 workspace layout (elements)
#define WT_OFF 0
#define Q_OFF  196608
#define K_OFF  (Q_OFF + 1048576)
#define VT_OFF (K_OFF + 1048576)
#define BF16_WS_ELEMS (VT_OFF + 1048576)   // 3,342,336 el -> 6,684,672 bytes

// ---------------------------------------------------------------------------
// Kernel 0: WT[n][k] = W_sel[k][n&63] bf16 (scale*log2e folded into Wq rows).
// Coalesced WRITES (consecutive tid -> consecutive k); strided reads hit L2.
// ---------------------------------------------------------------------------
__global__ void wt_kernel(const float* __restrict__ Wq, const float* __restrict__ Wk,
                          const float* __restrict__ Wv, bf16_t* __restrict__ WT) {
    int idx = blockIdx.x * 256 + threadIdx.x;   // idx = n*1024 + k
    int n = idx >> 10;
    int k = idx & 1023;
    const float* W = (n < 64) ? Wq : (n < 128) ? Wk : Wv;
    float s = (n < 64) ? 0.1803368801111204f : 1.0f;   // H^-0.5 * log2(e)
    WT[idx] = (bf16_t)(W[(size_t)k * 64 + (n & 63)] * s);
}

// ---------------------------------------------------------------------------
// Kernel 1: QKV projection, LDS-staged, double-buffered, ONE barrier/chunk.
// 512 blocks (32-row M-tiles, 2 blocks/CU), 256 thr. Wave w: all 32 rows x
// n-subtiles {3w..3w+2}.
// ---------------------------------------------------------------------------
__launch_bounds__(256)
__global__ void proj_kernel(const float* __restrict__ x, const bf16_t* __restrict__ WT,
                            bf16_t* __restrict__ q, bf16_t* __restrict__ kmat,
                            bf16_t* __restrict__ vt) {
    __shared__ bf16_t xs[2][32][72];     // +8 pad: row stride 144B -> 2-way banks (free)
    __shared__ bf16_t wsb[2][192][72];

    const int tid  = threadIdx.x;
    const int wave = tid >> 6;
    const int lane = tid & 63;
    const int l15  = lane & 15;
    const int quad = lane >> 4;
    const int m0   = blockIdx.x * 32;
    const int xrow = tid >> 3;           // 0..31
    const int xc8  = tid & 7;            // 8-el col chunk

    f32x4 acc[3][2];
#pragma unroll
    for (int nn = 0; nn < 3; ++nn)
#pragma unroll
        for (int rt = 0; rt < 2; ++rt)
            acc[nn][rt] = (f32x4){0.f, 0.f, 0.f, 0.f};

    float4 xa, xb;
    uint4 wr[6];

    // ---- load chunk k0 into registers ----
#define LOAD_CHUNK(k0)                                                          \
    {                                                                           \
        const float* xp = x + (size_t)(m0 + xrow) * Cn + (k0) + xc8 * 8;        \
        xa = *(const float4*)xp;  xb = *(const float4*)(xp + 4);                \
        _Pragma("unroll")                                                       \
        for (int i = 0; i < 6; ++i) {                                           \
            int id = i * 256 + tid;  int n = id >> 3;  int c8 = id & 7;         \
            wr[i] = *(const uint4*)(WT + (size_t)n * 1024 + (k0) + c8 * 8);     \
        }                                                                       \
    }
    // ---- store registers into LDS buffer nb ----
#define STORE_CHUNK(nb)                                                         \
    {                                                                           \
        bf16_t* dx = &xs[nb][xrow][xc8 * 8];                                    \
        dx[0] = (bf16_t)xa.x; dx[1] = (bf16_t)xa.y; dx[2] = (bf16_t)xa.z;       \
        dx[3] = (bf16_t)xa.w; dx[4] = (bf16_t)xb.x; dx[5] = (bf16_t)xb.y;       \
        dx[6] = (bf16_t)xb.z; dx[7] = (bf16_t)xb.w;                             \
        _Pragma("unroll")                                                       \
        for (int i = 0; i < 6; ++i) {                                           \
            int id = i * 256 + tid;  int n = id >> 3;  int c8 = id & 7;         \
            *(uint4*)&wsb[nb][n][c8 * 8] = wr[i];                               \
        }                                                                       \
    }

    LOAD_CHUNK(0);
    STORE_CHUNK(0);
    __syncthreads();

    for (int c = 0; c < 16; ++c) {
        const int nb = c & 1;
        if (c < 15) LOAD_CHUNK((c + 1) * 64);      // overlap with compute below
#pragma unroll
        for (int kk = 0; kk < 64; kk += 32) {
            bf16x8 af[2];
#pragma unroll
            for (int rt = 0; rt < 2; ++rt)
                af[rt] = *(const bf16x8*)&xs[nb][rt * 16 + l15][kk + quad * 8];
#pragma unroll
            for (int nn = 0; nn < 3; ++nn) {
                bf16x8 bfr = *(const bf16x8*)&wsb[nb][(wave * 3 + nn) * 16 + l15][kk + quad * 8];
#pragma unroll
                for (int rt = 0; rt < 2; ++rt)
                    acc[nn][rt] = __builtin_amdgcn_mfma_f32_16x16x32_bf16(af[rt], bfr, acc[nn][rt], 0, 0, 0);
            }
        }
        if (c < 15) STORE_CHUNK(1 - nb);
        __syncthreads();
    }

    // epilogue: C/D layout col=lane&15, row=quad*4+reg
#pragma unroll
    for (int nn = 0; nn < 3; ++nn) {
        int n = (wave * 3 + nn) * 16 + l15;    // 0..191
#pragma unroll
        for (int rt = 0; rt < 2; ++rt) {
#pragma unroll
            for (int r = 0; r < 4; ++r) {
                int row = m0 + rt * 16 + quad * 4 + r;
                float v = acc[nn][rt][r];
                if (n < 64) {
                    q[(size_t)row * Hn + n] = (bf16_t)v;
                } else if (n < 128) {
                    kmat[(size_t)row * Hn + (n - 64)] = (bf16_t)v;
                } else {
                    int b  = row >> 12;
                    int tr = row & (Tn - 1);
                    vt[((size_t)b * Hn + (n - 128)) * Tn + tr] = (bf16_t)v;
                }
            }
        }
    }
#undef LOAD_CHUNK
#undef STORE_CHUNK
}

// ---------------------------------------------------------------------------
// Kernel 2: split-KV causal flash attention. LDS-staged K/V, double-buffered,
// ONE barrier per unit. No running max (scores bounded: exp2 safe; scale
// cancels in combine). Grid (NSMAX, 64, B). 46 KB LDS -> 3 blocks/CU.
// ---------------------------------------------------------------------------
__launch_bounds__(256)
__global__ void attn_part(const bf16_t* __restrict__ q, const bf16_t* __restrict__ kmat,
                          const bf16_t* __restrict__ vt, float* __restrict__ Opart,
                          float* __restrict__ lpart, int UPS, int NSMAX) {
    __shared__ bf16_t kbuf[2][64][72];
    __shared__ bf16_t vbuf[2][64][72];
    __shared__ bf16_t p_lds[4][16][72];

    const int tid  = threadIdx.x;
    const int wave = tid >> 6;
    const int lane = tid & 63;
    const int l15  = lane & 15;
    const int quad = lane >> 4;
    const int split = blockIdx.x;
    const int t     = blockIdx.y;   // q-tile 0..63
    const int b     = blockIdx.z;

    const int nsplit = t / UPS + 1;
    if (split >= nsplit) return;
    const int u0 = split * UPS;
    const int u1 = min(u0 + UPS, t + 1);
    const int q0 = t * 64;

    size_t qbase = ((size_t)b * Tn + q0 + wave * 16 + l15) * Hn;
    bf16x8 qf0 = *(const bf16x8*)(q + qbase + quad * 8);
    bf16x8 qf1 = *(const bf16x8*)(q + qbase + 32 + quad * 8);

    const bf16_t* kb = kmat + (size_t)b * Tn * Hn;
    const bf16_t* vb = vt + (size_t)b * Hn * Tn;

    f32x4 acc_o[4];
#pragma unroll
    for (int i = 0; i < 4; ++i) acc_o[i] = (f32x4){0.f, 0.f, 0.f, 0.f};
    float lsum[4] = {0.f, 0.f, 0.f, 0.f};

    uint4 kr[2], vr[2];
    // staging: 2 uint4 per thread per tile (64 rows x 8 chunks of 16B = 512 slots)
#define LOAD_UNIT(u)                                                            \
    {                                                                           \
        const int s0l = (u) * 64;                                               \
        _Pragma("unroll")                                                       \
        for (int i = 0; i < 2; ++i) {                                           \
            int id = i * 256 + tid;  int row = id >> 3;  int c8 = id & 7;       \
            kr[i] = *(const uint4*)(kb + (size_t)(s0l + row) * Hn + c8 * 8);    \
            vr[i] = *(const uint4*)(vb + (size_t)row * Tn + s0l + c8 * 8);      \
        }                                                                       \
    }
#define STORE_UNIT(nb)                                                          \
    {                                                                           \
        _Pragma("unroll")                                                       \
        for (int i = 0; i < 2; ++i) {                                           \
            int id = i * 256 + tid;  int row = id >> 3;  int c8 = id & 7;       \
            *(uint4*)&kbuf[nb][row][c8 * 8] = kr[i];                            \
            *(uint4*)&vbuf[nb][row][c8 * 8] = vr[i];                            \
        }                                                                       \
    }

    LOAD_UNIT(u0);
    STORE_UNIT(0);
    __syncthreads();

    for (int u = u0; u < u1; ++u) {
        const int pb = (u - u0) & 1;
        if (u + 1 < u1) LOAD_UNIT(u + 1);        // overlap with compute

        // ---- S = Q K^T (scale pre-folded into q) ----
        f32x4 accs[4];
#pragma unroll
        for (int ts = 0; ts < 4; ++ts) accs[ts] = (f32x4){0.f, 0.f, 0.f, 0.f};
#pragma unroll
        for (int ts = 0; ts < 4; ++ts) {
            bf16x8 kf0 = *(const bf16x8*)&kbuf[pb][ts * 16 + l15][quad * 8];
            bf16x8 kf1 = *(const bf16x8*)&kbuf[pb][ts * 16 + l15][32 + quad * 8];
            accs[ts] = __builtin_amdgcn_mfma_f32_16x16x32_bf16(qf0, kf0, accs[ts], 0, 0, 0);
            accs[ts] = __builtin_amdgcn_mfma_f32_16x16x32_bf16(qf1, kf1, accs[ts], 0, 0, 0);
        }
        // ---- causal mask (diag unit only; wave-uniform branch) ----
        if (u == t) {
            const int rowb = q0 + wave * 16 + quad * 4;
            const int s0 = u * 64;
#pragma unroll
            for (int ts = 0; ts < 4; ++ts) {
                int col = s0 + ts * 16 + l15;
#pragma unroll
                for (int r = 0; r < 4; ++r)
                    accs[ts][r] = (col > rowb + r) ? -128.f : accs[ts][r];
            }
        }
        // ---- P = exp2(S); per-lane l; P -> wave-private LDS (C->A layout) ----
#pragma unroll
        for (int ts = 0; ts < 4; ++ts) {
#pragma unroll
            for (int r = 0; r < 4; ++r) {
                float p = exp2f(accs[ts][r]);
                lsum[r] += p;
                p_lds[wave][quad * 4 + r][ts * 16 + l15] = (bf16_t)p;
            }
        }
        // ---- O += P V ----
#pragma unroll
        for (int kk = 0; kk < 64; kk += 32) {
            bf16x8 pf = *(const bf16x8*)&p_lds[wave][l15][kk + quad * 8];
#pragma unroll
            for (int t2 = 0; t2 < 4; ++t2) {
                bf16x8 vf = *(const bf16x8*)&vbuf[pb][t2 * 16 + l15][kk + quad * 8];
                acc_o[t2] = __builtin_amdgcn_mfma_f32_16x16x32_bf16(pf, vf, acc_o[t2], 0, 0, 0);
            }
        }
        if (u + 1 < u1) STORE_UNIT(1 - pb);
        __syncthreads();
    }

    // ---- one deferred cross-lane l reduction ----
#pragma unroll
    for (int r = 0; r < 4; ++r) {
        float v = lsum[r];
        v += __shfl_xor(v, 1);
        v += __shfl_xor(v, 2);
        v += __shfl_xor(v, 4);
        v += __shfl_xor(v, 8);
        lsum[r] = v;
    }
    // ---- write partials (unnormalized O, l) ----
    size_t pbase = ((size_t)(b * 64 + t) * NSMAX + split) * 4096;
#pragma unroll
    for (int t2 = 0; t2 < 4; ++t2)
#pragma unroll
        for (int r = 0; r < 4; ++r)
            Opart[pbase + (size_t)(wave * 16 + quad * 4 + r) * 64 + t2 * 16 + l15] = acc_o[t2][r];
    if (l15 == 0) {
        size_t lb = ((size_t)(b * 64 + t) * NSMAX + split) * 64;
#pragma unroll
        for (int r = 0; r < 4; ++r)
            lpart[lb + wave * 16 + quad * 4 + r] = lsum[r];
    }
#undef LOAD_UNIT
#undef STORE_UNIT
}

// ---------------------------------------------------------------------------
// Kernel 3: combine partials (plain sums). Grid (64, B).
// ---------------------------------------------------------------------------
__launch_bounds__(256)
__global__ void combine_kernel(const float* __restrict__ Opart, const float* __restrict__ lpart,
                               float* __restrict__ out, int UPS, int NSMAX) {
    const int t = blockIdx.x;
    const int b = blockIdx.y;
    const int ns = t / UPS + 1;
    const int tid = threadIdx.x;
    const int row = tid >> 2;
    const int cg  = tid & 3;

    size_t pbase = (size_t)(b * 64 + t) * NSMAX * 4096;
    size_t lbase = (size_t)(b * 64 + t) * NSMAX * 64;

    float L = 0.f;
    float4 o[4];
#pragma unroll
    for (int i = 0; i < 4; ++i) o[i] = (float4){0.f, 0.f, 0.f, 0.f};
    for (int s = 0; s < ns; ++s) {
        L += lpart[lbase + s * 64 + row];
        const float4* src = (const float4*)(Opart + pbase + (size_t)s * 4096 + (size_t)row * 64 + cg * 16);
#pragma unroll
        for (int i = 0; i < 4; ++i) {
            float4 v = src[i];
            o[i].x += v.x; o[i].y += v.y; o[i].z += v.z; o[i].w += v.w;
        }
    }
    float inv = 1.f / L;
    float* dst = out + ((size_t)b * Tn + t * 64 + row) * Hn + cg * 16;
#pragma unroll
    for (int i = 0; i < 4; ++i) {
        float4 v = o[i];
        v.x *= inv; v.y *= inv; v.z *= inv; v.w *= inv;
        ((float4*)dst)[i] = v;
    }
}

// ---------------------------------------------------------------------------
extern "C" void kernel_launch(void* const* d_in, const int* in_sizes, int n_in,
                              void* d_out, int out_size, void* d_ws, size_t ws_size,
                              hipStream_t stream) {
    const float* x  = (const float*)d_in[0];
    const float* Wq = (const float*)d_in[1];
    const float* Wk = (const float*)d_in[2];
    const float* Wv = (const float*)d_in[3];
    float* out = (float*)d_out;

    bf16_t* wsb = (bf16_t*)d_ws;
    bf16_t* WT = wsb + WT_OFF;
    bf16_t* qb = wsb + Q_OFF;
    bf16_t* kb = wsb + K_OFF;
    bf16_t* vt = wsb + VT_OFF;

    const size_t base = (size_t)BF16_WS_ELEMS * 2;   // bytes used by bf16 region
    int NSMAX = 8;
    while (NSMAX > 1) {
        size_t need = base + (size_t)NSMAX * Bn * 64 * 4096 * 4      // Opart
                           + (size_t)NSMAX * Bn * 64 * 64 * 4;       // lpart
        if (need <= ws_size) break;
        NSMAX >>= 1;
    }
    const int UPS = 64 / NSMAX;

    float* Opart = (float*)((char*)d_ws + base);
    float* lpart = Opart + (size_t)NSMAX * Bn * 64 * 4096;

    wt_kernel<<<dim3(192 * 1024 / 256), dim3(256), 0, stream>>>(Wq, Wk, Wv, WT);
    proj_kernel<<<dim3((Bn * Tn) / 32), dim3(256), 0, stream>>>(x, WT, qb, kb, vt);
    attn_part<<<dim3(NSMAX, Tn / 64, Bn), dim3(256), 0, stream>>>(qb, kb, vt, Opart, lpart, UPS, NSMAX);
    combine_kernel<<<dim3(Tn / 64, Bn), dim3(256), 0, stream>>>(Opart, lpart, out, UPS, NSMAX);
}